// Round 4
// baseline (576.023 us; speedup 1.0000x reference)
//
#include <hip/hip_runtime.h>

// FMLayer: out[b, p] = <w[j1], w[j2]> * x[b, j1] * x[b, j2] for triu pairs (j1<j2)
// N=512, K=4, B=1024, P=130816. Inputs fp32, output fp32.
//
// R6: index-free, conflict-free streaming.
//  - Two L2-resident tables in d_ws: wd[p] (f32) and idx[p] = (j1<<16)|j2 (u32).
//    Inner loop has NO sqrt / row-walk / branches: load wd+idx, 2x bfe,
//    2x LDS read, 2x mul, plain (non-NT) f32x2 store.
//  - f32x2 ownership: xs[j2] is a stride-2 LDS read across lanes = 2 lanes/bank
//    = conflict-free (m136); xs[j1] is broadcast. SQ_LDS_BANK_CONFLICT -> 0.
//  - Plain stores (match the 6.3 TB/s fill kernel's path); NT was unproven and
//    is the prime suspect for R5's 2.8 TB/s plateau alongside the LDS conflicts.
//  - grid = (1024 rows) x (2 half-rows) = 2048 blocks = 8/CU x 4 waves
//    = 32 waves/CU; each block writes one 262 KB contiguous stream.

#define NF      512
#define KDIM    4
#define BATCH   1024
#define NPAIRS  130816   // 512*511/2
#define WDPAD   131072   // NPAIRS padded (+256 entries)
#define TPB     256
#define SPLIT   2
#define PBLK    (WDPAD / SPLIT)        // 65536 pair-slots per block
#define VEC     2
#define STEP    (TPB * VEC)            // 512 pairs per iteration
#define NIT     (PBLK / STEP)          // 128 iterations
#define BT      16                     // fallback path only

typedef float        f32x2 __attribute__((ext_vector_type(2)));
typedef float        f32x4 __attribute__((ext_vector_type(4)));
typedef unsigned int u32x2 __attribute__((ext_vector_type(2)));

__device__ __forceinline__ int rowoff(int j) {
    return (j * (1023 - j)) >> 1;      // start offset of row j1=j
}

// ---------- kernel 1: wd + idx tables (1 MB) + pad ----------
__global__ __launch_bounds__(TPB) void fm_tab(
    const float* __restrict__ w,       // [NF, KDIM]
    float* __restrict__ wd,            // [WDPAD]
    unsigned int* __restrict__ idx)    // [WDPAD]
{
    const int j1 = blockIdx.x;
    if (j1 == NF - 1) {                // pad block: zero [NPAIRS, WDPAD)
        wd[NPAIRS + threadIdx.x]  = 0.f;
        idx[NPAIRS + threadIdx.x] = 0u;
        return;
    }
    const int L   = (NF - 1) - j1;
    const int off = rowoff(j1);
    const float wa0 = w[j1*KDIM+0], wa1 = w[j1*KDIM+1],
                wa2 = w[j1*KDIM+2], wa3 = w[j1*KDIM+3];
    for (int t = threadIdx.x; t < L; t += TPB) {
        const int j2 = j1 + 1 + t;
        wd[off + t]  = wa0*w[j2*KDIM+0] + wa1*w[j2*KDIM+1]
                     + wa2*w[j2*KDIM+2] + wa3*w[j2*KDIM+3];
        idx[off + t] = ((unsigned)j1 << 16) | (unsigned)j2;
    }
}

// ---------- kernel 2: index-free streaming main ----------
__global__ __launch_bounds__(TPB) void fm_main3(
    const float* __restrict__ x,             // [BATCH, NF]
    const float* __restrict__ wd,            // [WDPAD]
    const unsigned int* __restrict__ idx,    // [WDPAD]
    float* __restrict__ out)                 // [BATCH, NPAIRS]
{
    __shared__ float xs[NF];                 // 2 KB; only LDS use

    const int b = blockIdx.x;
    const int t = threadIdx.x;

    if (t < NF / 4)
        reinterpret_cast<f32x4*>(xs)[t] =
            reinterpret_cast<const f32x4*>(x + (size_t)b * NF)[t];
    __syncthreads();                         // the only barrier

    const int pbase = blockIdx.y * PBLK;
    float* const obase = out + (size_t)b * NPAIRS;

    int p = pbase + (t << 1);
    // prefetch rotation: iter i+1's loads issue before iter i's store, so the
    // load-use wait never drains outstanding stores.
    f32x2 wv = *reinterpret_cast<const f32x2*>(wd + p);
    u32x2 iv = *reinterpret_cast<const u32x2*>(idx + p);

    for (int it = 0; it < NIT; ++it, p += STEP) {
        f32x2 nw = (f32x2){0.f, 0.f};
        u32x2 ni = (u32x2){0u, 0u};
        if (it + 1 < NIT) {
            nw = *reinterpret_cast<const f32x2*>(wd + p + STEP);
            ni = *reinterpret_cast<const u32x2*>(idx + p + STEP);
        }

        if (p < NPAIRS) {   // p even, NPAIRS even => group fully valid
            const int j1a = iv.x >> 16, j2a = iv.x & 0xffff;
            const int j1b = iv.y >> 16, j2b = iv.y & 0xffff;
            f32x2 o;
            o.x = wv.x * xs[j1a] * xs[j2a];  // xs[j1*]: broadcast; xs[j2*]: stride-2
            o.y = wv.y * xs[j1b] * xs[j2b];
            *reinterpret_cast<f32x2*>(obase + p) = o;   // plain store (fill path)
        }
        wv = nw; iv = ni;
    }
}

// ---------- fallback tier 1 (R5 sqrt-walk) if ws fits only wd ----------
__global__ __launch_bounds__(TPB) void fm_wdot(
    const float* __restrict__ w, float* __restrict__ wd)
{
    const int j1 = blockIdx.x;
    if (j1 == NF - 1) { wd[NPAIRS + threadIdx.x] = 0.f; return; }
    const int L   = (NF - 1) - j1;
    const int off = rowoff(j1);
    const float wa0 = w[j1*KDIM+0], wa1 = w[j1*KDIM+1],
                wa2 = w[j1*KDIM+2], wa3 = w[j1*KDIM+3];
    for (int t = threadIdx.x; t < L; t += TPB) {
        const int j2 = j1 + 1 + t;
        wd[off + t] = wa0*w[j2*KDIM+0] + wa1*w[j2*KDIM+1]
                    + wa2*w[j2*KDIM+2] + wa3*w[j2*KDIM+3];
    }
}

__global__ __launch_bounds__(TPB) void fm_main2(
    const float* __restrict__ x, const float* __restrict__ wd,
    float* __restrict__ out)
{
    __shared__ float xs[NF];
    const int b = blockIdx.x;
    const int t = threadIdx.x;
    if (t < NF / 4)
        reinterpret_cast<f32x4*>(xs)[t] =
            reinterpret_cast<const f32x4*>(x + (size_t)b * NF)[t];
    __syncthreads();

    const int pbase = blockIdx.y * PBLK;
    float* const obase = out + (size_t)b * NPAIRS;
    f32x4 wv = *reinterpret_cast<const f32x4*>(wd + pbase + (t << 2));

    const int NIT4 = PBLK / (TPB * 4);
    for (int it = 0; it < NIT4; ++it) {
        const int p = pbase + it * (TPB * 4) + (t << 2);
        f32x4 nwv = (f32x4){0.f, 0.f, 0.f, 0.f};
        if (it + 1 < NIT4)
            nwv = *reinterpret_cast<const f32x4*>(wd + p + TPB * 4);
        if (p < NPAIRS) {
            const float s = sqrtf((float)(1046529 - 8 * p));
            int j1 = (int)((1023.0f - s) * 0.5f);
            j1 = j1 < 0 ? 0 : (j1 > 510 ? 510 : j1);
            int len = 511 - j1;
            int r   = (j1 * (1023 - j1)) >> 1;
            while (r > p)        { --j1; ++len; r -= len; }
            while (p >= r + len) { r += len; --len; ++j1; }
            float xj1 = xs[j1];
            f32x4 o;
            o.x = wv.x * xj1 * xs[p     - r + j1 + 1];
            if (p + 1 >= r + len) { r += len; --len; ++j1; xj1 = xs[j1]; }
            o.y = wv.y * xj1 * xs[p + 1 - r + j1 + 1];
            if (p + 2 >= r + len) { r += len; --len; ++j1; xj1 = xs[j1]; }
            o.z = wv.z * xj1 * xs[p + 2 - r + j1 + 1];
            if (p + 3 >= r + len) { r += len; --len; ++j1; xj1 = xs[j1]; }
            o.w = wv.w * xj1 * xs[p + 3 - r + j1 + 1];
            *reinterpret_cast<f32x4*>(obase + p) = o;
        }
        wv = nwv;
    }
}

// ---------- fallback tier 2 (no workspace) ----------
__global__ __launch_bounds__(TPB) void fm_kernel(
    const float* __restrict__ x, const float* __restrict__ w,
    float* __restrict__ out)
{
    const int j1  = blockIdx.x;
    const int b0  = blockIdx.y * BT;
    const int L   = (NF - 1) - j1;
    const int off = j1 * (NF - 1) - (j1 * (j1 - 1)) / 2;
    const float wa0 = w[j1*KDIM+0], wa1 = w[j1*KDIM+1],
                wa2 = w[j1*KDIM+2], wa3 = w[j1*KDIM+3];
    __shared__ float wdl[NF - 1];
    for (int t = threadIdx.x; t < L; t += TPB) {
        const int j2 = j1 + 1 + t;
        wdl[t] = wa0*w[j2*KDIM+0] + wa1*w[j2*KDIM+1]
               + wa2*w[j2*KDIM+2] + wa3*w[j2*KDIM+3];
    }
    __syncthreads();
    for (int bi = 0; bi < BT; ++bi) {
        const int b = b0 + bi;
        const float xj1 = x[(size_t)b * NF + j1];
        const float* __restrict__ xrow = x + (size_t)b * NF + (j1 + 1);
        float* __restrict__ orow = out + (size_t)b * NPAIRS + off;
        for (int t = threadIdx.x; t < L; t += TPB)
            orow[t] = wdl[t] * xj1 * xrow[t];
    }
}

extern "C" void kernel_launch(void* const* d_in, const int* in_sizes, int n_in,
                              void* d_out, int out_size, void* d_ws, size_t ws_size,
                              hipStream_t stream) {
    const float* x = (const float*)d_in[0];     // [1024, 512] fp32
    const float* w = (const float*)d_in[1];     // [512, 4]   fp32
    float* out = (float*)d_out;                 // [1024, 130816] fp32

    if (ws_size >= 2 * (size_t)WDPAD * sizeof(float)) {
        float* wd = (float*)d_ws;
        unsigned int* idx = (unsigned int*)d_ws + WDPAD;
        fm_tab<<<dim3(NF), TPB, 0, stream>>>(w, wd, idx);              // 512 blocks
        fm_main3<<<dim3(BATCH, SPLIT), TPB, 0, stream>>>(x, wd, idx, out);
    } else if (ws_size >= (size_t)WDPAD * sizeof(float)) {
        float* wd = (float*)d_ws;
        fm_wdot<<<dim3(NF), TPB, 0, stream>>>(w, wd);
        fm_main2<<<dim3(BATCH, SPLIT), TPB, 0, stream>>>(x, wd, out);
    } else {
        dim3 grid(NF - 1, BATCH / BT);
        fm_kernel<<<grid, TPB, 0, stream>>>(x, w, out);
    }
}